// Round 8
// baseline (127.212 us; speedup 1.0000x reference)
//
#include <hip/hip_runtime.h>
#include <cmath>

// bs=16, l=128, d=256.  Softmax over i cancels row-constant terms -> W2, attn_b drop.
//   xhid_{t+1} = m*(G2_t + cA_t) + agg_b,   G2_t = xhid_t @ M1^T,  M1 = agg_w@U1
//   cA_t = v0 + M2@agg_t,  M2 = agg_w@U2,  v0 = agg_w@upd_b
//   s1_{t+1} = xhid_{t+1}@W1^T == xhid_t@KS^T + row-const (mask==1), KS = W1*M1
//   out = xhid_3@U1^T + c3,  c3 = upd_b + U2@agg_3
// All W operands pre-packed as contiguous panels [256 k][128 c] for LDS staging.

constexpr int PAN = 256 * 128;   // floats per panel

// ---------------- panel chunk staging (16 KB = 32 k-rows) ----------------
__device__ inline void loadc(const float* __restrict__ P, int ch, int tid, float4 (&st)[4]) {
    const float4* g = (const float4*)(P + (size_t)ch * 4096);
    st[0] = g[tid]; st[1] = g[256 + tid]; st[2] = g[512 + tid]; st[3] = g[768 + tid];
}
__device__ inline void storec(float* Wl, int tid, const float4 (&st)[4]) {
    float4* d = (float4*)Wl;
    d[tid] = st[0]; d[256 + tid] = st[1]; d[512 + tid] = st[2]; d[768 + tid] = st[3];
}

// ---------------- GEMM cores (W from LDS, double-buffered) ----------------
// 128-col: lane owns cols {2l,2l+1}; acc[4][2]
__device__ inline void gemm128(const float (&As)[16][264], const float* __restrict__ P,
                               float* Wl, int tid, int lane, int rw, float (&acc)[4][2]) {
    float4 st[4];
    loadc(P, 0, tid, st); storec(Wl, tid, st);
    __syncthreads();
    for (int ch = 0; ch < 8; ++ch) {
        if (ch < 7) loadc(P, ch + 1, tid, st);
        const float* Wc = Wl + (ch & 1) * 4096;
        #pragma unroll
        for (int kq = 0; kq < 8; ++kq) {
            const int kl = 4 * kq;
            const float* wr = Wc + kl * 128 + 2 * lane;
            float2 w0 = *(const float2*)(wr);
            float2 w1 = *(const float2*)(wr + 128);
            float2 w2 = *(const float2*)(wr + 256);
            float2 w3 = *(const float2*)(wr + 384);
            const int k = ch * 32 + kl;
            float4 a0 = *(const float4*)&As[rw + 0][k];
            float4 a1 = *(const float4*)&As[rw + 1][k];
            float4 a2 = *(const float4*)&As[rw + 2][k];
            float4 a3 = *(const float4*)&As[rw + 3][k];
#define RS(r, ar)                                         \
            acc[r][0] = fmaf(ar.x, w0.x, acc[r][0]);      \
            acc[r][0] = fmaf(ar.y, w1.x, acc[r][0]);      \
            acc[r][0] = fmaf(ar.z, w2.x, acc[r][0]);      \
            acc[r][0] = fmaf(ar.w, w3.x, acc[r][0]);      \
            acc[r][1] = fmaf(ar.x, w0.y, acc[r][1]);      \
            acc[r][1] = fmaf(ar.y, w1.y, acc[r][1]);      \
            acc[r][1] = fmaf(ar.z, w2.y, acc[r][1]);      \
            acc[r][1] = fmaf(ar.w, w3.y, acc[r][1]);
            RS(0, a0) RS(1, a1) RS(2, a2) RS(3, a3)
#undef RS
        }
        if (ch < 7) { storec(Wl + ((ch + 1) & 1) * 4096, tid, st); __syncthreads(); }
    }
}

// dual 64-col panel [M1 | KS]: lane owns col l of each half; ag2/as3[4]
__device__ inline void gemm64x2(const float (&As)[16][264], const float* __restrict__ P,
                                float* Wl, int tid, int lane, int rw,
                                float (&ag2)[4], float (&as3)[4]) {
    float4 st[4];
    loadc(P, 0, tid, st); storec(Wl, tid, st);
    __syncthreads();
    for (int ch = 0; ch < 8; ++ch) {
        if (ch < 7) loadc(P, ch + 1, tid, st);
        const float* Wc = Wl + (ch & 1) * 4096;
        #pragma unroll
        for (int kq = 0; kq < 8; ++kq) {
            const int kl = 4 * kq;
            const float* wr = Wc + kl * 128 + lane;
            float wm0 = wr[0],   wm1 = wr[128], wm2 = wr[256], wm3 = wr[384];
            float wk0 = wr[64],  wk1 = wr[192], wk2 = wr[320], wk3 = wr[448];
            const int k = ch * 32 + kl;
            #pragma unroll
            for (int r = 0; r < 4; ++r) {
                float4 ar = *(const float4*)&As[rw + r][k];
                ag2[r] = fmaf(ar.x, wm0, ag2[r]);
                ag2[r] = fmaf(ar.y, wm1, ag2[r]);
                ag2[r] = fmaf(ar.z, wm2, ag2[r]);
                ag2[r] = fmaf(ar.w, wm3, ag2[r]);
                as3[r] = fmaf(ar.x, wk0, as3[r]);
                as3[r] = fmaf(ar.y, wk1, as3[r]);
                as3[r] = fmaf(ar.z, wk2, as3[r]);
                as3[r] = fmaf(ar.w, wk3, as3[r]);
            }
        }
        if (ch < 7) { storec(Wl + ((ch + 1) & 1) * 4096, tid, st); __syncthreads(); }
    }
}

// ---------------- misc helpers ----------------
// 32x32-tile transpose into plain [k][dld] matrix
__device__ inline void transp(const float* __restrict__ src, int sld, int scol0,
                              float* __restrict__ dst, int dld,
                              int ti, int tt, float* lds) {
    const int tr = (ti >> 3) * 32, tc = (ti & 7) * 32;
    const int rr = tt >> 5, cc = tt & 31;
    #pragma unroll
    for (int p = 0; p < 4; ++p) {
        int row = p * 8 + rr;
        lds[row * 33 + cc] = src[(size_t)(tr + row) * sld + scol0 + tc + cc];
    }
    __syncthreads();
    #pragma unroll
    for (int p = 0; p < 4; ++p) {
        int krow = p * 8 + rr;
        dst[(size_t)(tc + krow) * dld + tr + cc] = lds[cc * 33 + krow];
    }
    __syncthreads();
}

// 32x32-tile transpose into panel layout [slice][256][128], slice = e>>7
__device__ inline void transp_pan(const float* __restrict__ src, int sld, int scol0,
                                  float* __restrict__ pans,
                                  int ti, int tt, float* lds) {
    const int tr = (ti >> 3) * 32, tc = (ti & 7) * 32;
    const int rr = tt >> 5, cc = tt & 31;
    #pragma unroll
    for (int p = 0; p < 4; ++p) {
        int row = p * 8 + rr;
        lds[row * 33 + cc] = src[(size_t)(tr + row) * sld + scol0 + tc + cc];
    }
    __syncthreads();
    float* base = pans + (size_t)(tr >> 7) * PAN + (tr & 127);
    #pragma unroll
    for (int p = 0; p < 4; ++p) {
        int krow = p * 8 + rr;
        base[(size_t)(tc + krow) * 128 + cc] = lds[cc * 33 + krow];
    }
    __syncthreads();
}

// stage 16x256 A-tile into LDS. AMODE 0: plain; 2: m*(src+cadd)+aggb
template<int AMODE>
__device__ inline void stageA(const float* __restrict__ src, const float* __restrict__ maskp,
                              const float* __restrict__ aggb, const float* __restrict__ cadd,
                              int r0, int tt, float (&As)[16][264]) {
    const int row = tt >> 4, k4 = (tt & 15) * 16;
    const float* sp = src + (size_t)(r0 + row) * 256 + k4;
    float mv = (AMODE != 0) ? maskp[r0 + row] : 1.f;
    #pragma unroll
    for (int j = 0; j < 4; ++j) {
        float4 v = *(const float4*)(sp + 4 * j);
        if (AMODE == 2) {
            float4 c4 = *(const float4*)(cadd + k4 + 4 * j);
            float4 b4 = *(const float4*)(aggb + k4 + 4 * j);
            v.x = fmaf(mv, v.x + c4.x, b4.x);
            v.y = fmaf(mv, v.y + c4.y, b4.y);
            v.z = fmaf(mv, v.z + c4.z, b4.z);
            v.w = fmaf(mv, v.w + c4.w, b4.w);
        }
        *(float4*)&As[row][k4 + 4 * j] = v;
    }
}

// ---------------------------------------------------------------------------
// L0: 0..63 M1 (-> wpA slices 2,3 + wpB M1-halves) | 64..127 M2^T -> m2t |
//     128..191 W1^T -> wpA slices 0,1 | 192..255 U1^T -> u1p | 256..319 U2^T |
//     320 v0 | 321..448 G0 (64x64 LDS-tiled)
// ---------------------------------------------------------------------------
__global__ __launch_bounds__(256) void l0_k(
    const float* __restrict__ feat, const float* __restrict__ mask,
    const float* __restrict__ agg_w, const float* __restrict__ agg_b,
    const float* __restrict__ attn_w, const float* __restrict__ upd_w,
    const float* __restrict__ upd_b,
    float* __restrict__ wpA, float* __restrict__ wpB, float* __restrict__ u1p,
    float* __restrict__ m2t, float* __restrict__ u2t,
    float* __restrict__ v0, float* __restrict__ buf0)
{
    const int bid = blockIdx.x, t = threadIdx.x;
    __shared__ __align__(16) float shb[4352];

    if (bid < 128) {
        // M[e,f] = sum_d agg_w[e,d]*upd_w[d*512 + co + f]
        const int co = (bid < 64) ? 0 : 256;
        const int e0 = (bid & 63) * 4;
        float (&agL)[4][256] = *(float (*)[4][256])shb;
        {
            int row = t >> 6, d0 = (t & 63) * 4;
            *(float4*)&agL[row][d0] = *(const float4*)(agg_w + (size_t)(e0 + row) * 256 + d0);
        }
        __syncthreads();
        float acc[4] = {0.f, 0.f, 0.f, 0.f};
        #pragma unroll 4
        for (int d = 0; d < 256; ++d) {
            float u = upd_w[(size_t)d * 512 + co + t];
            acc[0] = fmaf(agL[0][d], u, acc[0]);
            acc[1] = fmaf(agL[1][d], u, acc[1]);
            acc[2] = fmaf(agL[2][d], u, acc[2]);
            acc[3] = fmaf(agL[3][d], u, acc[3]);
        }
        if (bid < 64) {
            #pragma unroll
            for (int i = 0; i < 4; ++i) {
                int e = e0 + i;
                wpA[(size_t)(2 + (e >> 7)) * PAN + (size_t)t * 128 + (e & 127)] = acc[i];
                wpB[(size_t)(e >> 6) * PAN + (size_t)t * 128 + (e & 63)] = acc[i];
            }
        } else {
            #pragma unroll
            for (int i = 0; i < 4; ++i)
                m2t[(size_t)t * 256 + e0 + i] = acc[i];   // m2t[d][e] = M2[e][d]
        }
    } else if (bid < 192) {
        transp_pan(attn_w, 512, 0, wpA, bid - 128, t, shb);     // W1^T -> slices 0,1
    } else if (bid < 256) {
        transp_pan(upd_w, 512, 0, u1p, bid - 192, t, shb);      // U1^T
    } else if (bid < 320) {
        transp(upd_w, 512, 256, u2t, 256, bid - 256, t, shb);   // U2^T
    } else if (bid == 320) {
        float* ub = shb;
        ub[t] = upd_b[t];
        __syncthreads();
        float acc = 0.f;
        const float* wr = agg_w + (size_t)t * 256;
        #pragma unroll 8
        for (int d = 0; d < 256; ++d) acc = fmaf(wr[d], ub[d], acc);
        v0[t] = acc;
    } else {
        // G0: xhid_1 = (feat*mask)@agg_w^T + agg_b  (64x64 LDS-tiled)
        const int v  = bid - 321;
        const int r0 = (v & 31) * 64, e0 = (v >> 5) * 64;
        float* As2 = shb;
        float* Bs2 = shb + 2176;
        const int tx = t & 15, ty = t >> 4;
        float acc[4][4] = {};
        for (int k0 = 0; k0 < 256; k0 += 32) {
            #pragma unroll
            for (int tp = t; tp < 512; tp += 256) {
                int row = tp >> 3, kk = (tp & 7) << 2;
                float4 vv = *(const float4*)(feat + (size_t)(r0 + row) * 256 + k0 + kk);
                float mv = mask[r0 + row];
                As2[(kk + 0) * 68 + row] = vv.x * mv;
                As2[(kk + 1) * 68 + row] = vv.y * mv;
                As2[(kk + 2) * 68 + row] = vv.z * mv;
                As2[(kk + 3) * 68 + row] = vv.w * mv;
            }
            #pragma unroll
            for (int tp = t; tp < 512; tp += 256) {
                int row = tp >> 3, kk = (tp & 7) << 2;
                float4 vv = *(const float4*)(agg_w + (size_t)(e0 + row) * 256 + k0 + kk);
                Bs2[(kk + 0) * 68 + row] = vv.x;
                Bs2[(kk + 1) * 68 + row] = vv.y;
                Bs2[(kk + 2) * 68 + row] = vv.z;
                Bs2[(kk + 3) * 68 + row] = vv.w;
            }
            __syncthreads();
            #pragma unroll
            for (int kk = 0; kk < 32; ++kk) {
                float4 av = *(const float4*)&As2[kk * 68 + (ty << 2)];
                float4 bv = *(const float4*)&Bs2[kk * 68 + (tx << 2)];
                float a[4] = {av.x, av.y, av.z, av.w};
                float bb[4] = {bv.x, bv.y, bv.z, bv.w};
                #pragma unroll
                for (int i = 0; i < 4; ++i)
                    #pragma unroll
                    for (int j = 0; j < 4; ++j)
                        acc[i][j] = fmaf(a[i], bb[j], acc[i][j]);
            }
            __syncthreads();
        }
        #pragma unroll
        for (int i = 0; i < 4; ++i) {
            int r = r0 + (ty << 2) + i;
            #pragma unroll
            for (int j = 0; j < 4; ++j) {
                int e = e0 + (tx << 2) + j;
                buf0[(size_t)r * 256 + e] = acc[i][j] + agg_b[e];
            }
        }
    }
}

// ---------------------------------------------------------------------------
// BIG1: bid<512: [s1_1|G2_1] + step-1 stats.  bid>=512: KS^T -> wpB KS-halves.
// ---------------------------------------------------------------------------
__global__ __launch_bounds__(256) void big1_k(
    const float* __restrict__ Asrc, const float* __restrict__ wpA,
    float* __restrict__ wpB,
    const float* __restrict__ mask, const float* __restrict__ agg_b,
    const float* __restrict__ attn_w,
    float* __restrict__ g2dst, float* __restrict__ pzout, float* __restrict__ paout)
{
    __shared__ __align__(16) float As[16][264];
    __shared__ __align__(16) float Wl[2][4096];
    const int t = threadIdx.x, lane = t & 63, wv = t >> 6, rw = wv * 4;
    const int bid = blockIdx.x;

    if (bid >= 512) {
        // KS^T[k][e] = sum_d W1[e,d]*M1[d,k] -> wpB[e>>6][k][64+(e&63)]
        const int k0 = (bid - 512) * 4;
        float (&agL)[4][256] = *(float (*)[4][256])(&As[0][0]);
        {
            int row = t >> 6, d0 = (t & 63) * 4;
            *(float4*)&agL[row][d0] = *(const float4*)(
                wpA + (size_t)(2 + (d0 >> 7)) * PAN + (size_t)(k0 + row) * 128 + (d0 & 127));
        }
        __syncthreads();
        float acc[4] = {0.f, 0.f, 0.f, 0.f};
        const size_t wbase = (size_t)(t >> 7) * PAN + (t & 127);
        #pragma unroll 4
        for (int d = 0; d < 256; ++d) {
            float w = wpA[wbase + (size_t)d * 128];   // W1^T[d][t] = W1[t,d]
            acc[0] = fmaf(agL[0][d], w, acc[0]);
            acc[1] = fmaf(agL[1][d], w, acc[1]);
            acc[2] = fmaf(agL[2][d], w, acc[2]);
            acc[3] = fmaf(agL[3][d], w, acc[3]);
        }
        #pragma unroll
        for (int i = 0; i < 4; ++i)
            wpB[(size_t)(t >> 6) * PAN + (size_t)(k0 + i) * 128 + 64 + (t & 63)] = acc[i];
        return;
    }

    const int bx = bid >> 2, by = bid & 3;
    const int r0 = bx * 16;
    stageA<0>(Asrc, mask, agg_b, nullptr, r0, t, As);
    // no standalone barrier: gemm's chunk-0 barrier covers As too

    float acc[4][2] = {};
    gemm128(As, wpA + (size_t)by * PAN, &Wl[0][0], t, lane, rw, acc);

    if (by < 2) {
        const int gg = bx * 4 + wv;
        const int e = by * 128 + 2 * lane;
        float pzv[2], pav[2];
        #pragma unroll
        for (int c = 0; c < 2; ++c) {
            float p0 = __expf(acc[0][c]);
            float p1 = __expf(acc[1][c]);
            float p2 = __expf(acc[2][c]);
            float p3 = __expf(acc[3][c]);
            const int ee = e + c;
            pav[c] = p0 * As[rw + 0][ee] + p1 * As[rw + 1][ee]
                   + p2 * As[rw + 2][ee] + p3 * As[rw + 3][ee];
            pzv[c] = (p0 + p1) + (p2 + p3);
        }
        *(float2*)(pzout + (size_t)gg * 256 + e) = make_float2(pzv[0], pzv[1]);
        *(float2*)(paout + (size_t)gg * 256 + e) = make_float2(pav[0], pav[1]);
    } else {
        const int e = (by - 2) * 128 + 2 * lane;
        #pragma unroll
        for (int r = 0; r < 4; ++r)
            *(float2*)(g2dst + (size_t)(r0 + rw + r) * 256 + e) =
                make_float2(acc[r][0], acc[r][1]);
    }
}

// ---------------------------------------------------------------------------
// BIG2: grid 128x6.  Prologue: agg_1 -> cA_1.
//   by<2 : s1_2 (W1 panel) + step-2 stats
//   by>=2: q=by-2: [M1|KS] panel -> G2_2 (buf) + step-3 partials
// ---------------------------------------------------------------------------
__global__ __launch_bounds__(256) void big2_k(
    const float* __restrict__ Asrc, const float* __restrict__ wpA,
    const float* __restrict__ wpB,
    const float* __restrict__ m2t, const float* __restrict__ v0,
    const float* __restrict__ mask, const float* __restrict__ agg_b,
    const float* __restrict__ pzin, const float* __restrict__ pain,
    float* __restrict__ g2dst,
    float* __restrict__ pz1, float* __restrict__ pa1,
    float* __restrict__ pz2, float* __restrict__ pa2)
{
    __shared__ __align__(16) float As[16][264];
    __shared__ __align__(16) float Wl[2][4096];
    __shared__ float aggL[256];
    __shared__ __align__(16) float caL[256];

    const int t = threadIdx.x, lane = t & 63, wv = t >> 6, rw = wv * 4;
    const int bid = blockIdx.x;
    const int bx = bid / 6, by = bid - bx * 6;
    const int r0 = bx * 16, b = bx >> 3;

    {   // prologue: merge step-1 partials -> agg_1 -> cA_1
        float z = 0.f, a = 0.f;
        #pragma unroll 8
        for (int g = 0; g < 32; ++g) {
            size_t idx = (size_t)(b * 32 + g) * 256 + t;
            z += pzin[idx]; a += pain[idx];
        }
        aggL[t] = 1.f / (1.f + __expf(-(a / z)));
        __syncthreads();
        float ca = v0[t];
        #pragma unroll 8
        for (int d = 0; d < 256; ++d)
            ca = fmaf(aggL[d], m2t[(size_t)d * 256 + t], ca);
        caL[t] = ca;
        __syncthreads();
    }
    stageA<2>(Asrc, mask, agg_b, caL, r0, t, As);

    if (by < 2) {
        float acc[4][2] = {};
        gemm128(As, wpA + (size_t)by * PAN, &Wl[0][0], t, lane, rw, acc);
        const int gg = bx * 4 + wv;
        const int e = by * 128 + 2 * lane;
        float pzv[2], pav[2];
        #pragma unroll
        for (int c = 0; c < 2; ++c) {
            float p0 = __expf(acc[0][c]);
            float p1 = __expf(acc[1][c]);
            float p2 = __expf(acc[2][c]);
            float p3 = __expf(acc[3][c]);
            const int ee = e + c;
            pav[c] = p0 * As[rw + 0][ee] + p1 * As[rw + 1][ee]
                   + p2 * As[rw + 2][ee] + p3 * As[rw + 3][ee];
            pzv[c] = (p0 + p1) + (p2 + p3);
        }
        *(float2*)(pz1 + (size_t)gg * 256 + e) = make_float2(pzv[0], pzv[1]);
        *(float2*)(pa1 + (size_t)gg * 256 + e) = make_float2(pav[0], pav[1]);
    } else {
        const int q = by - 2;
        float ag2[4] = {}, as3[4] = {};
        gemm64x2(As, wpB + (size_t)q * PAN, &Wl[0][0], t, lane, rw, ag2, as3);
        const int e = q * 64 + lane;
        #pragma unroll
        for (int r = 0; r < 4; ++r)
            g2dst[(size_t)(r0 + rw + r) * 256 + e] = ag2[r];
        float p0 = __expf(as3[0]);
        float p1 = __expf(as3[1]);
        float p2 = __expf(as3[2]);
        float p3 = __expf(as3[3]);
        float z  = (p0 + p1) + (p2 + p3);
        float am = p0 * ag2[0] + p1 * ag2[1] + p2 * ag2[2] + p3 * ag2[3];
        const int gg = bx * 4 + wv;
        pz2[(size_t)gg * 256 + e] = z;
        pa2[(size_t)gg * 256 + e] = am;
    }
}

// ---------------------------------------------------------------------------
// BIG3: grid 128x2.  Prologues: agg_2->cA_2; agg_3=sigmoid(Am/Z+cA_2+agg_b)->c3.
//       Main: out = xhid_3 @ U1^T + c3.
// ---------------------------------------------------------------------------
__global__ __launch_bounds__(256) void big3_k(
    const float* __restrict__ Asrc, const float* __restrict__ u1p,
    const float* __restrict__ u2t,
    const float* __restrict__ m2t, const float* __restrict__ v0,
    const float* __restrict__ mask, const float* __restrict__ agg_b,
    const float* __restrict__ pzin, const float* __restrict__ pain,
    const float* __restrict__ pz2, const float* __restrict__ pa2,
    const float* __restrict__ upd_b, float* __restrict__ outp)
{
    __shared__ __align__(16) float As[16][264];
    __shared__ __align__(16) float Wl[2][4096];
    __shared__ float aggL[256];
    __shared__ __align__(16) float caL[256];
    __shared__ float a3L[256];
    __shared__ __align__(16) float c3L[256];

    const int t = threadIdx.x, lane = t & 63, wv = t >> 6, rw = wv * 4;
    const int bid = blockIdx.x;
    const int bx = bid >> 1, by = bid & 1;
    const int r0 = bx * 16, b = bx >> 3;

    {   // agg_2 -> cA_2
        float z = 0.f, a = 0.f;
        #pragma unroll 8
        for (int g = 0; g < 32; ++g) {
            size_t idx = (size_t)(b * 32 + g) * 256 + t;
            z += pzin[idx]; a += pain[idx];
        }
        aggL[t] = 1.f / (1.f + __expf(-(a / z)));
        __syncthreads();
        float ca = v0[t];
        #pragma unroll 8
        for (int d = 0; d < 256; ++d)
            ca = fmaf(aggL[d], m2t[(size_t)d * 256 + t], ca);
        caL[t] = ca;
    }
    {   // agg_3 -> c3
        float z = 0.f, a = 0.f;
        #pragma unroll 8
        for (int g = 0; g < 32; ++g) {
            size_t idx = (size_t)(b * 32 + g) * 256 + t;
            z += pz2[idx]; a += pa2[idx];
        }
        float Aval = a / z + caL[t] + agg_b[t];
        a3L[t] = 1.f / (1.f + __expf(-Aval));
        __syncthreads();
        float c3 = upd_b[t];
        #pragma unroll 8
        for (int d = 0; d < 256; ++d)
            c3 = fmaf(a3L[d], u2t[(size_t)d * 256 + t], c3);
        c3L[t] = c3;
        __syncthreads();
    }
    stageA<2>(Asrc, mask, agg_b, caL, r0, t, As);

    float acc[4][2] = {};
    gemm128(As, u1p + (size_t)by * PAN, &Wl[0][0], t, lane, rw, acc);

    const int e = by * 128 + 2 * lane;
    float cx = c3L[e], cy = c3L[e + 1];
    #pragma unroll
    for (int r = 0; r < 4; ++r)
        *(float2*)(outp + (size_t)(r0 + rw + r) * 256 + e) =
            make_float2(acc[r][0] + cx, acc[r][1] + cy);
}

// ---------------------------------------------------------------------------
extern "C" void kernel_launch(void* const* d_in, const int* in_sizes, int n_in,
                              void* d_out, int out_size, void* d_ws, size_t ws_size,
                              hipStream_t stream) {
    const float* feat   = (const float*)d_in[0];
    const float* mask   = (const float*)d_in[1];
    const float* agg_w  = (const float*)d_in[2];
    const float* agg_b  = (const float*)d_in[3];
    const float* attn_w = (const float*)d_in[4];   // attn_b (d_in[5]) & W2 cancel
    const float* upd_w  = (const float*)d_in[6];
    const float* upd_b  = (const float*)d_in[7];
    float* out = (float*)d_out;

    float* p   = (float*)d_ws;
    float* wpA = p; p += 4 * PAN;    // [W1^T 0:128 | W1^T 128:256 | M1^T 0:128 | M1^T 128:256]
    float* wpB = p; p += 4 * PAN;    // q: [M1^T 64q:64q+64 | KS^T 64q:64q+64]
    float* u1p = p; p += 2 * PAN;    // U1^T panels
    float* m2t = p; p += 256 * 256;
    float* u2t = p; p += 256 * 256;
    float* v0  = p; p += 256;
    float* buf0 = p; p += 2048 * 256;
    float* buf1 = p; p += 2048 * 256;
    float* pz0 = p; p += 512 * 256;
    float* pa0 = p; p += 512 * 256;
    float* pz1 = p; p += 512 * 256;
    float* pa1 = p; p += 512 * 256;
    float* pz2 = p; p += 512 * 256;
    float* pa2 = p; p += 512 * 256;

    l0_k<<<449, 256, 0, stream>>>(feat, mask, agg_w, agg_b, attn_w, upd_w, upd_b,
                                  wpA, wpB, u1p, m2t, u2t, v0, buf0);
    big1_k<<<576, 256, 0, stream>>>(buf0, wpA, wpB, mask, agg_b, attn_w,
                                    buf1, pz0, pa0);
    big2_k<<<768, 256, 0, stream>>>(buf1, wpA, wpB, m2t, v0, mask, agg_b,
                                    pz0, pa0, buf0, pz1, pa1, pz2, pa2);
    big3_k<<<256, 256, 0, stream>>>(buf0, u1p, u2t, m2t, v0, mask, agg_b,
                                    pz1, pa1, pz2, pa2, upd_b, out);
}

// Round 9
// 108.781 us; speedup vs baseline: 1.1694x; 1.1694x over previous
//
#include <hip/hip_runtime.h>
#include <cmath>

// bs=16, l=128, d=256.  Softmax over i cancels row-constant terms -> W2, attn_b drop.
//   xhid_{t+1} = m*(G2_t + cA_t) + agg_b,  G2_t = xhid_t@M1^T,  M1 = agg_w@U1
//   cA_t = v0 + M2@agg_t,  M2 = agg_w@U2,  v0 = agg_w@upd_b
//   s1_3 row-var part: S3 = xhid_2@KS^T,   KS = W1*M1  (mask==1)
//   out = xhid_3@U1^T + c3,  c3 = upd_b + U2@agg_3
// All weight operands k-major [k][cols]; 64x64-tile GEMM, As/Bs[32][68], 3 blk/CU.

#define FMA16(av,bv,acc)                                                        \
  acc[0][0]=fmaf(av.x,bv.x,acc[0][0]); acc[0][1]=fmaf(av.x,bv.y,acc[0][1]);     \
  acc[0][2]=fmaf(av.x,bv.z,acc[0][2]); acc[0][3]=fmaf(av.x,bv.w,acc[0][3]);     \
  acc[1][0]=fmaf(av.y,bv.x,acc[1][0]); acc[1][1]=fmaf(av.y,bv.y,acc[1][1]);     \
  acc[1][2]=fmaf(av.y,bv.z,acc[1][2]); acc[1][3]=fmaf(av.y,bv.w,acc[1][3]);     \
  acc[2][0]=fmaf(av.z,bv.x,acc[2][0]); acc[2][1]=fmaf(av.z,bv.y,acc[2][1]);     \
  acc[2][2]=fmaf(av.z,bv.z,acc[2][2]); acc[2][3]=fmaf(av.z,bv.w,acc[2][3]);     \
  acc[3][0]=fmaf(av.w,bv.x,acc[3][0]); acc[3][1]=fmaf(av.w,bv.y,acc[3][1]);     \
  acc[3][2]=fmaf(av.w,bv.z,acc[3][2]); acc[3][3]=fmaf(av.w,bv.w,acc[3][3]);

// ---- 64x64 GEMM: A 64x256 (transform on stage), W k-major [k][wld], cols c0..c0+63
// AMODE 0: plain; 1: *mask[r]; 2: m*(src+caL)+aggb
template<int AMODE>
__device__ __forceinline__ void gemm64(
    const float* __restrict__ Asrc, const float* __restrict__ Wt, int wld, int c0,
    int r0, const float* __restrict__ maskp, const float* __restrict__ aggb,
    const float* caL, float* As, float* Bs, int t, float (&acc)[4][4])
{
    const int tx = t & 15, ty = t >> 4;
    const int ar = t >> 3, ak = (t & 7) << 2;
    const int bk = t >> 4, bc4 = (t & 15) << 2;
    for (int k0 = 0; k0 < 256; k0 += 32) {
        #pragma unroll
        for (int h = 0; h < 2; ++h) {
            const int row = ar + 32 * h;
            float4 v = *(const float4*)(Asrc + (size_t)(r0 + row) * 256 + k0 + ak);
            if (AMODE == 1) {
                const float mv = maskp[r0 + row];
                v.x *= mv; v.y *= mv; v.z *= mv; v.w *= mv;
            } else if (AMODE == 2) {
                const float mv = maskp[r0 + row];
                float4 c4 = *(const float4*)(caL + k0 + ak);
                float4 b4 = *(const float4*)(aggb + k0 + ak);
                v.x = fmaf(mv, v.x + c4.x, b4.x);
                v.y = fmaf(mv, v.y + c4.y, b4.y);
                v.z = fmaf(mv, v.z + c4.z, b4.z);
                v.w = fmaf(mv, v.w + c4.w, b4.w);
            }
            As[(ak + 0) * 68 + row] = v.x; As[(ak + 1) * 68 + row] = v.y;
            As[(ak + 2) * 68 + row] = v.z; As[(ak + 3) * 68 + row] = v.w;
        }
        #pragma unroll
        for (int h = 0; h < 2; ++h) {
            const int kk = bk + 16 * h;
            float4 w = *(const float4*)(Wt + (size_t)(k0 + kk) * wld + c0 + bc4);
            *(float4*)&Bs[kk * 68 + bc4] = w;
        }
        __syncthreads();
        #pragma unroll
        for (int kk = 0; kk < 32; ++kk) {
            float4 av = *(const float4*)&As[kk * 68 + ty * 4];
            float4 bv = *(const float4*)&Bs[kk * 68 + tx * 4];
            FMA16(av, bv, acc)
        }
        __syncthreads();
    }
}

// softmax-partial epilogue: 4-row groups, re-reads xh patch from global
template<int AMODE>
__device__ __forceinline__ void stats_epi(
    const float* __restrict__ Asrc, const float* __restrict__ maskp,
    const float* __restrict__ aggb, const float* caL,
    int r0, int c0, int bx, int t, const float (&acc)[4][4],
    float* __restrict__ pz, float* __restrict__ pa)
{
    const int tx = t & 15, ty = t >> 4;
    const int e = c0 + tx * 4;
    float xh[4][4];
    #pragma unroll
    for (int i = 0; i < 4; ++i) {
        const int r = r0 + ty * 4 + i;
        float4 v = *(const float4*)(Asrc + (size_t)r * 256 + e);
        if (AMODE == 2) {
            const float mv = maskp[r];
            float4 c4 = *(const float4*)(caL + e);
            float4 b4 = *(const float4*)(aggb + e);
            v.x = fmaf(mv, v.x + c4.x, b4.x);
            v.y = fmaf(mv, v.y + c4.y, b4.y);
            v.z = fmaf(mv, v.z + c4.z, b4.z);
            v.w = fmaf(mv, v.w + c4.w, b4.w);
        }
        xh[i][0] = v.x; xh[i][1] = v.y; xh[i][2] = v.z; xh[i][3] = v.w;
    }
    float pzv[4], pav[4];
    #pragma unroll
    for (int j = 0; j < 4; ++j) {
        float p0 = __expf(acc[0][j]), p1 = __expf(acc[1][j]);
        float p2 = __expf(acc[2][j]), p3 = __expf(acc[3][j]);
        pzv[j] = (p0 + p1) + (p2 + p3);
        pav[j] = fmaf(p0, xh[0][j], fmaf(p1, xh[1][j], fmaf(p2, xh[2][j], p3 * xh[3][j])));
    }
    const int gg = bx * 16 + ty;
    *(float4*)(pz + (size_t)gg * 256 + e) = make_float4(pzv[0], pzv[1], pzv[2], pzv[3]);
    *(float4*)(pa + (size_t)gg * 256 + e) = make_float4(pav[0], pav[1], pav[2], pav[3]);
}

__device__ __forceinline__ void write_epi(float* __restrict__ dst, int r0, int c0,
                                          int t, const float (&acc)[4][4]) {
    const int tx = t & 15, ty = t >> 4;
    const int e = c0 + tx * 4;
    #pragma unroll
    for (int i = 0; i < 4; ++i)
        *(float4*)(dst + (size_t)(r0 + ty * 4 + i) * 256 + e) =
            make_float4(acc[i][0], acc[i][1], acc[i][2], acc[i][3]);
}

// 32x32-tile transpose: dst[k][e] = src[e*sld + scol0 + k]
__device__ inline void transp(const float* __restrict__ src, int sld, int scol0,
                              float* __restrict__ dst, int dld,
                              int ti, int tt, float* lds) {
    const int tr = (ti >> 3) * 32, tc = (ti & 7) * 32;
    const int rr = tt >> 5, cc = tt & 31;
    #pragma unroll
    for (int p = 0; p < 4; ++p) {
        int row = p * 8 + rr;
        lds[row * 33 + cc] = src[(size_t)(tr + row) * sld + scol0 + tc + cc];
    }
    __syncthreads();
    #pragma unroll
    for (int p = 0; p < 4; ++p) {
        int krow = p * 8 + rr;
        dst[(size_t)(tc + krow) * dld + tr + cc] = lds[cc * 33 + krow];
    }
    __syncthreads();
}

// ---------------------------------------------------------------------------
// L0: 0..63 M1^T->wt12[:,256:] | 64..127 M2^T->m2t | 128..191 W1^T->wt12[:,:256]
//     192..255 U1^T->u1t | 256..319 U2^T->u2t | 320 v0 | 321..448 G0
// ---------------------------------------------------------------------------
__global__ __launch_bounds__(256) void l0_k(
    const float* __restrict__ feat, const float* __restrict__ mask,
    const float* __restrict__ agg_w, const float* __restrict__ agg_b,
    const float* __restrict__ attn_w, const float* __restrict__ upd_w,
    const float* __restrict__ upd_b,
    float* __restrict__ wt12, float* __restrict__ u1t, float* __restrict__ u2t,
    float* __restrict__ m2t, float* __restrict__ v0, float* __restrict__ buf0)
{
    const int bid = blockIdx.x, t = threadIdx.x;
    __shared__ __align__(16) float shb[4352];

    if (bid < 128) {
        const int co = (bid < 64) ? 0 : 256;
        const int e0 = (bid & 63) * 4;
        float (&agL)[4][256] = *(float (*)[4][256])shb;
        {
            int row = t >> 6, d0 = (t & 63) * 4;
            *(float4*)&agL[row][d0] = *(const float4*)(agg_w + (size_t)(e0 + row) * 256 + d0);
        }
        __syncthreads();
        float acc[4] = {0.f, 0.f, 0.f, 0.f};
        #pragma unroll 4
        for (int d = 0; d < 256; ++d) {
            float u = upd_w[(size_t)d * 512 + co + t];
            acc[0] = fmaf(agL[0][d], u, acc[0]);
            acc[1] = fmaf(agL[1][d], u, acc[1]);
            acc[2] = fmaf(agL[2][d], u, acc[2]);
            acc[3] = fmaf(agL[3][d], u, acc[3]);
        }
        if (bid < 64) {
            #pragma unroll
            for (int i = 0; i < 4; ++i)
                wt12[(size_t)t * 512 + 256 + e0 + i] = acc[i];     // M1^T
        } else {
            #pragma unroll
            for (int i = 0; i < 4; ++i)
                m2t[(size_t)t * 256 + e0 + i] = acc[i];            // m2t[d][e]=M2[e,d]
        }
    } else if (bid < 192) {
        transp(attn_w, 512, 0, wt12, 512, bid - 128, t, shb);      // W1^T
    } else if (bid < 256) {
        transp(upd_w, 512, 0, u1t, 256, bid - 192, t, shb);        // U1^T
    } else if (bid < 320) {
        transp(upd_w, 512, 256, u2t, 256, bid - 256, t, shb);      // U2^T
    } else if (bid == 320) {
        float* ub = shb;
        ub[t] = upd_b[t];
        __syncthreads();
        float acc = 0.f;
        const float* wr = agg_w + (size_t)t * 256;
        #pragma unroll 8
        for (int d = 0; d < 256; ++d) acc = fmaf(wr[d], ub[d], acc);
        v0[t] = acc;
    } else {
        // G0: xhid_1 = (feat*mask)@agg_w^T + agg_b  (A and B both transpose-staged)
        const int v = bid - 321;
        const int r0 = (v & 31) * 64, e0 = (v >> 5) * 64;
        float* As = shb; float* Bs = shb + 2176;
        const int tx = t & 15, ty = t >> 4;
        const int ar = t >> 3, ak = (t & 7) << 2;
        float acc[4][4] = {};
        for (int k0 = 0; k0 < 256; k0 += 32) {
            #pragma unroll
            for (int h = 0; h < 2; ++h) {
                const int row = ar + 32 * h;
                float4 va = *(const float4*)(feat + (size_t)(r0 + row) * 256 + k0 + ak);
                const float mv = mask[r0 + row];
                As[(ak + 0) * 68 + row] = va.x * mv; As[(ak + 1) * 68 + row] = va.y * mv;
                As[(ak + 2) * 68 + row] = va.z * mv; As[(ak + 3) * 68 + row] = va.w * mv;
                float4 vb = *(const float4*)(agg_w + (size_t)(e0 + row) * 256 + k0 + ak);
                Bs[(ak + 0) * 68 + row] = vb.x; Bs[(ak + 1) * 68 + row] = vb.y;
                Bs[(ak + 2) * 68 + row] = vb.z; Bs[(ak + 3) * 68 + row] = vb.w;
            }
            __syncthreads();
            #pragma unroll
            for (int kk = 0; kk < 32; ++kk) {
                float4 av = *(const float4*)&As[kk * 68 + ty * 4];
                float4 bv = *(const float4*)&Bs[kk * 68 + tx * 4];
                FMA16(av, bv, acc)
            }
            __syncthreads();
        }
        const int e = e0 + tx * 4;
        float4 b4 = *(const float4*)(agg_b + e);
        #pragma unroll
        for (int i = 0; i < 4; ++i)
            *(float4*)(buf0 + (size_t)(r0 + ty * 4 + i) * 256 + e) =
                make_float4(acc[i][0] + b4.x, acc[i][1] + b4.y,
                            acc[i][2] + b4.z, acc[i][3] + b4.w);
    }
}

// ---------------------------------------------------------------------------
// BIG1: grid (40,8). bx<32: [s1_1|G2_1] GEMM; by<4 stats1, by>=4 G2_1->buf1.
//       bx>=32: KS^T prep -> kst[d][e]=KS[e,d], KS=W1*M1.
// ---------------------------------------------------------------------------
__global__ __launch_bounds__(256) void big1_k(
    const float* __restrict__ buf0, const float* __restrict__ wt12,
    const float* __restrict__ mask,
    float* __restrict__ kst, float* __restrict__ buf1,
    float* __restrict__ pz0, float* __restrict__ pa0)
{
    __shared__ __align__(16) float shb[4352];
    const int t = threadIdx.x;
    const int bx = blockIdx.x, by = blockIdx.y;

    if (bx >= 32) {   // KS prep
        const int k0 = ((bx - 32) * 8 + by) * 4;
        float (&agL)[4][256] = *(float (*)[4][256])shb;
        {
            int row = t >> 6, d0 = (t & 63) * 4;
            *(float4*)&agL[row][d0] =
                *(const float4*)(wt12 + (size_t)(k0 + row) * 512 + 256 + d0);
        }
        __syncthreads();
        float acc[4] = {0.f, 0.f, 0.f, 0.f};
        #pragma unroll 4
        for (int d = 0; d < 256; ++d) {
            float w = wt12[(size_t)d * 512 + t];
            acc[0] = fmaf(agL[0][d], w, acc[0]);
            acc[1] = fmaf(agL[1][d], w, acc[1]);
            acc[2] = fmaf(agL[2][d], w, acc[2]);
            acc[3] = fmaf(agL[3][d], w, acc[3]);
        }
        #pragma unroll
        for (int i = 0; i < 4; ++i)
            kst[(size_t)(k0 + i) * 256 + t] = acc[i];
        return;
    }

    float* As = shb; float* Bs = shb + 2176;
    const int r0 = bx * 64;
    const int c0 = (by < 4) ? by * 64 : 256 + (by - 4) * 64;
    float acc[4][4] = {};
    gemm64<0>(buf0, wt12, 512, c0, r0, nullptr, nullptr, nullptr, As, Bs, t, acc);
    if (by < 4)
        stats_epi<0>(buf0, nullptr, nullptr, nullptr, r0, c0, bx, t, acc, pz0, pa0);
    else
        write_epi(buf1, r0, c0 - 256, t, acc);
}

// ---------------------------------------------------------------------------
// BIG2: grid (32,12). Prologue (all): agg_1 -> cA_1.
//   by<4: s1_2 + stats2 -> pz1/pa1 ; by 4..7: G2_2 -> buf0 ; by 8..11: S3 -> buf2
// ---------------------------------------------------------------------------
__global__ __launch_bounds__(256) void big2_k(
    const float* __restrict__ buf1, const float* __restrict__ wt12,
    const float* __restrict__ kst,
    const float* __restrict__ m2t, const float* __restrict__ v0,
    const float* __restrict__ mask, const float* __restrict__ agg_b,
    const float* __restrict__ pz0, const float* __restrict__ pa0,
    float* __restrict__ buf0, float* __restrict__ buf2,
    float* __restrict__ pz1, float* __restrict__ pa1)
{
    __shared__ __align__(16) float shb[4864];
    float* As = shb; float* Bs = shb + 2176;
    float* aggL = shb + 4352; float* caL = shb + 4608;

    const int t = threadIdx.x;
    const int bx = blockIdx.x, by = blockIdx.y;
    const int r0 = bx * 64, b = bx >> 1;

    {   // prologue: merge step-1 partials -> agg_1 -> cA_1
        float z = 0.f, a = 0.f;
        #pragma unroll 8
        for (int g = 0; g < 32; ++g) {
            size_t idx = (size_t)(b * 32 + g) * 256 + t;
            z += pz0[idx]; a += pa0[idx];
        }
        aggL[t] = 1.f / (1.f + __expf(-(a / z)));
        __syncthreads();
        float ca = v0[t];
        #pragma unroll 8
        for (int d = 0; d < 256; ++d)
            ca = fmaf(aggL[d], m2t[(size_t)d * 256 + t], ca);
        caL[t] = ca;
        __syncthreads();
    }

    float acc[4][4] = {};
    if (by < 4) {
        const int c0 = by * 64;
        gemm64<2>(buf1, wt12, 512, c0, r0, mask, agg_b, caL, As, Bs, t, acc);
        stats_epi<2>(buf1, mask, agg_b, caL, r0, c0, bx, t, acc, pz1, pa1);
    } else if (by < 8) {
        const int c0 = 256 + (by - 4) * 64;
        gemm64<2>(buf1, wt12, 512, c0, r0, mask, agg_b, caL, As, Bs, t, acc);
        write_epi(buf0, r0, c0 - 256, t, acc);
    } else {
        const int c0 = (by - 8) * 64;
        gemm64<2>(buf1, kst, 256, c0, r0, mask, agg_b, caL, As, Bs, t, acc);
        write_epi(buf2, r0, c0, t, acc);
    }
}

// ---------------------------------------------------------------------------
// BIG3: grid (64,4), 32x64 tiles.  Prologue: agg_2->cA_2; scan S3/G2_2 -> agg_3 -> c3.
//       Main: out = xhid_3 @ U1^T + c3.
// ---------------------------------------------------------------------------
__global__ __launch_bounds__(256) void big3_k(
    const float* __restrict__ buf0, const float* __restrict__ buf2,
    const float* __restrict__ u1t, const float* __restrict__ u2t,
    const float* __restrict__ m2t, const float* __restrict__ v0,
    const float* __restrict__ mask, const float* __restrict__ agg_b,
    const float* __restrict__ pz1, const float* __restrict__ pa1,
    const float* __restrict__ upd_b, float* __restrict__ outp)
{
    __shared__ __align__(16) float shb[4352];
    float* As2 = shb;              // [32][36]
    float* Bs  = shb + 1152;       // [32][68]
    float* aggL = shb + 3328;
    float* caL  = shb + 3584;
    float* a3L  = shb + 3840;
    float* c3L  = shb + 4096;

    const int t = threadIdx.x;
    const int bx = blockIdx.x, by = blockIdx.y;
    const int r0 = bx * 32, b = bx >> 2;

    // --- prologue ---
    float ca;
    {
        float z = 0.f, a = 0.f;
        #pragma unroll 8
        for (int g = 0; g < 32; ++g) {
            size_t idx = (size_t)(b * 32 + g) * 256 + t;
            z += pz1[idx]; a += pa1[idx];
        }
        aggL[t] = 1.f / (1.f + __expf(-(a / z)));
        __syncthreads();
        ca = v0[t];
        #pragma unroll 8
        for (int d = 0; d < 256; ++d)
            ca = fmaf(aggL[d], m2t[(size_t)d * 256 + t], ca);
        caL[t] = ca;
    }
    {   // scan S3/G2_2 over this batch's 128 rows (thread t owns column t)
        float z2 = 0.f, a2 = 0.f;
        const float* s3p = buf2 + (size_t)b * 128 * 256 + t;
        const float* g2p = buf0 + (size_t)b * 128 * 256 + t;
        #pragma unroll 4
        for (int r = 0; r < 128; ++r) {
            float p = __expf(s3p[(size_t)r * 256]);
            z2 += p;
            a2 = fmaf(p, g2p[(size_t)r * 256], a2);
        }
        float A3 = a2 / z2 + ca + agg_b[t];
        a3L[t] = 1.f / (1.f + __expf(-A3));
        __syncthreads();
        float c3 = upd_b[t];
        #pragma unroll 8
        for (int d = 0; d < 256; ++d)
            c3 = fmaf(a3L[d], u2t[(size_t)d * 256 + t], c3);
        c3L[t] = c3;
        __syncthreads();
    }

    // --- 32x64 GEMM: out = xhid_3 @ U1^T ---
    const int tx = t & 15, ty = t >> 4;
    const int ar = t >> 3, ak = (t & 7) << 2;        // A: row 0..31
    const int bk = t >> 4, bc4 = (t & 15) << 2;
    const int c0 = by * 64;
    float acc[2][4] = {};
    for (int k0 = 0; k0 < 256; k0 += 32) {
        {
            const int row = ar;
            float4 v = *(const float4*)(buf0 + (size_t)(r0 + row) * 256 + k0 + ak);
            const float mv = mask[r0 + row];
            float4 c4 = *(const float4*)(caL + k0 + ak);
            float4 b4 = *(const float4*)(agg_b + k0 + ak);
            v.x = fmaf(mv, v.x + c4.x, b4.x);
            v.y = fmaf(mv, v.y + c4.y, b4.y);
            v.z = fmaf(mv, v.z + c4.z, b4.z);
            v.w = fmaf(mv, v.w + c4.w, b4.w);
            As2[(ak + 0) * 36 + row] = v.x; As2[(ak + 1) * 36 + row] = v.y;
            As2[(ak + 2) * 36 + row] = v.z; As2[(ak + 3) * 36 + row] = v.w;
        }
        #pragma unroll
        for (int h = 0; h < 2; ++h) {
            const int kk = bk + 16 * h;
            float4 w = *(const float4*)(u1t + (size_t)(k0 + kk) * 256 + c0 + bc4);
            *(float4*)&Bs[kk * 68 + bc4] = w;
        }
        __syncthreads();
        #pragma unroll
        for (int kk = 0; kk < 32; ++kk) {
            float2 a2v = *(const float2*)&As2[kk * 36 + ty * 2];
            float4 bv  = *(const float4*)&Bs[kk * 68 + tx * 4];
            acc[0][0]=fmaf(a2v.x,bv.x,acc[0][0]); acc[0][1]=fmaf(a2v.x,bv.y,acc[0][1]);
            acc[0][2]=fmaf(a2v.x,bv.z,acc[0][2]); acc[0][3]=fmaf(a2v.x,bv.w,acc[0][3]);
            acc[1][0]=fmaf(a2v.y,bv.x,acc[1][0]); acc[1][1]=fmaf(a2v.y,bv.y,acc[1][1]);
            acc[1][2]=fmaf(a2v.y,bv.z,acc[1][2]); acc[1][3]=fmaf(a2v.y,bv.w,acc[1][3]);
        }
        __syncthreads();
    }
    const int e = c0 + tx * 4;
    float4 cc = *(const float4*)&c3L[e];
    #pragma unroll
    for (int i = 0; i < 2; ++i)
        *(float4*)(outp + (size_t)(r0 + ty * 2 + i) * 256 + e) =
            make_float4(acc[i][0] + cc.x, acc[i][1] + cc.y,
                        acc[i][2] + cc.z, acc[i][3] + cc.w);
}

// ---------------------------------------------------------------------------
extern "C" void kernel_launch(void* const* d_in, const int* in_sizes, int n_in,
                              void* d_out, int out_size, void* d_ws, size_t ws_size,
                              hipStream_t stream) {
    const float* feat   = (const float*)d_in[0];
    const float* mask   = (const float*)d_in[1];
    const float* agg_w  = (const float*)d_in[2];
    const float* agg_b  = (const float*)d_in[3];
    const float* attn_w = (const float*)d_in[4];   // attn_b (d_in[5]) & W2 cancel
    const float* upd_w  = (const float*)d_in[6];
    const float* upd_b  = (const float*)d_in[7];
    float* out = (float*)d_out;

    float* p    = (float*)d_ws;
    float* wt12 = p; p += 256 * 512;   // [k][ W1^T | M1^T ]
    float* u1t  = p; p += 256 * 256;
    float* u2t  = p; p += 256 * 256;
    float* m2t  = p; p += 256 * 256;
    float* kst  = p; p += 256 * 256;   // KS^T
    float* v0   = p; p += 256;
    float* buf0 = p; p += 2048 * 256;
    float* buf1 = p; p += 2048 * 256;
    float* buf2 = p; p += 2048 * 256;  // S3
    float* pz0  = p; p += 512 * 256;
    float* pa0  = p; p += 512 * 256;
    float* pz1  = p; p += 512 * 256;
    float* pa1  = p; p += 512 * 256;

    // L0: weight prep + G0 (xhid_1 -> buf0)
    l0_k<<<449, 256, 0, stream>>>(feat, mask, agg_w, agg_b, attn_w, upd_w, upd_b,
                                  wt12, u1t, u2t, m2t, v0, buf0);
    // BIG1: stats1 -> pz0/pa0, G2_1 -> buf1; KS^T prep
    big1_k<<<dim3(40, 8), 256, 0, stream>>>(buf0, wt12, mask, kst, buf1, pz0, pa0);
    // BIG2: cA_1 prologue; stats2 -> pz1/pa1, G2_2 -> buf0, S3 -> buf2
    big2_k<<<dim3(32, 12), 256, 0, stream>>>(buf1, wt12, kst, m2t, v0, mask, agg_b,
                                             pz0, pa0, buf0, buf2, pz1, pa1);
    // BIG3: cA_2 + scan prologue; out = xhid_3 @ U1^T + c3
    big3_k<<<dim3(64, 4), 256, 0, stream>>>(buf0, buf2, u1t, u2t, m2t, v0, mask, agg_b,
                                            pz1, pa1, upd_b, out);
}

// Round 10
// 84.969 us; speedup vs baseline: 1.4972x; 1.2802x over previous
//
#include <hip/hip_runtime.h>
#include <cmath>

// bs=16, l=128, d=256.  Softmax over i cancels row-constant terms -> W2, attn_b drop.
//   xhid_{t+1} = m*(G2_t + cA_t) + agg_b,  G2_t = xhid_t@M1^T,  M1 = agg_w@U1
//   cA_t = v0 + M2@agg_t,  M2 = agg_w@U2,  v0 = agg_w@upd_b
//   s1_3 row-var part: S3 = xhid_2@KS^T,   KS = W1*M1  (mask==1)
//   out = xhid_3@U1^T + c3,  c3 = upd_b + U2@agg_3
// Per-batch scalar chains (agg/cA/c3) hoisted into ck1/ck2 (16 x 1024).

#define FMA16(av,bv,acc)                                                        \
  acc[0][0]=fmaf(av.x,bv.x,acc[0][0]); acc[0][1]=fmaf(av.x,bv.y,acc[0][1]);     \
  acc[0][2]=fmaf(av.x,bv.z,acc[0][2]); acc[0][3]=fmaf(av.x,bv.w,acc[0][3]);     \
  acc[1][0]=fmaf(av.y,bv.x,acc[1][0]); acc[1][1]=fmaf(av.y,bv.y,acc[1][1]);     \
  acc[1][2]=fmaf(av.y,bv.z,acc[1][2]); acc[1][3]=fmaf(av.y,bv.w,acc[1][3]);     \
  acc[2][0]=fmaf(av.z,bv.x,acc[2][0]); acc[2][1]=fmaf(av.z,bv.y,acc[2][1]);     \
  acc[2][2]=fmaf(av.z,bv.z,acc[2][2]); acc[2][3]=fmaf(av.z,bv.w,acc[2][3]);     \
  acc[3][0]=fmaf(av.w,bv.x,acc[3][0]); acc[3][1]=fmaf(av.w,bv.y,acc[3][1]);     \
  acc[3][2]=fmaf(av.w,bv.z,acc[3][2]); acc[3][3]=fmaf(av.w,bv.w,acc[3][3]);

// ---- 64x64 GEMM, reg-prefetch double-buffered stage.
// AMODE 0: A plain; 2: m*(src+caL)+abL  (caL/abL are LDS, k-indexed)
template<int AMODE>
__device__ __forceinline__ void gemm64(
    const float* __restrict__ Asrc, const float* __restrict__ Wt, int wld, int c0,
    int r0, const float* __restrict__ maskp, const float* abL,
    const float* caL, float* As, float* Bs, int t, float (&acc)[4][4])
{
    const int tx = t & 15, ty = t >> 4;
    const int ar = t >> 3, ak = (t & 7) << 2;
    const int bk = t >> 4, bc4 = (t & 15) << 2;
    float4 va0, va1, vb0, vb1;

    va0 = *(const float4*)(Asrc + (size_t)(r0 + ar) * 256 + ak);
    va1 = *(const float4*)(Asrc + (size_t)(r0 + ar + 32) * 256 + ak);
    vb0 = *(const float4*)(Wt + (size_t)bk * wld + c0 + bc4);
    vb1 = *(const float4*)(Wt + (size_t)(bk + 16) * wld + c0 + bc4);

    for (int ch = 0; ch < 8; ++ch) {
        const int k0 = ch * 32;
        // store staged regs (with A-transform)
        {
            float4 v = va0;
            if (AMODE == 2) {
                const float mv = maskp[r0 + ar];
                float4 c4 = *(const float4*)(caL + k0 + ak);
                float4 b4 = *(const float4*)(abL + k0 + ak);
                v.x = fmaf(mv, v.x + c4.x, b4.x); v.y = fmaf(mv, v.y + c4.y, b4.y);
                v.z = fmaf(mv, v.z + c4.z, b4.z); v.w = fmaf(mv, v.w + c4.w, b4.w);
            }
            As[(ak + 0) * 68 + ar] = v.x; As[(ak + 1) * 68 + ar] = v.y;
            As[(ak + 2) * 68 + ar] = v.z; As[(ak + 3) * 68 + ar] = v.w;
            v = va1;
            if (AMODE == 2) {
                const float mv = maskp[r0 + ar + 32];
                float4 c4 = *(const float4*)(caL + k0 + ak);
                float4 b4 = *(const float4*)(abL + k0 + ak);
                v.x = fmaf(mv, v.x + c4.x, b4.x); v.y = fmaf(mv, v.y + c4.y, b4.y);
                v.z = fmaf(mv, v.z + c4.z, b4.z); v.w = fmaf(mv, v.w + c4.w, b4.w);
            }
            As[(ak + 0) * 68 + ar + 32] = v.x; As[(ak + 1) * 68 + ar + 32] = v.y;
            As[(ak + 2) * 68 + ar + 32] = v.z; As[(ak + 3) * 68 + ar + 32] = v.w;
            *(float4*)&Bs[bk * 68 + bc4] = vb0;
            *(float4*)&Bs[(bk + 16) * 68 + bc4] = vb1;
        }
        __syncthreads();
        if (ch < 7) {   // prefetch next chunk; completes under the FMA block
            const int kn = k0 + 32;
            va0 = *(const float4*)(Asrc + (size_t)(r0 + ar) * 256 + kn + ak);
            va1 = *(const float4*)(Asrc + (size_t)(r0 + ar + 32) * 256 + kn + ak);
            vb0 = *(const float4*)(Wt + (size_t)(kn + bk) * wld + c0 + bc4);
            vb1 = *(const float4*)(Wt + (size_t)(kn + bk + 16) * wld + c0 + bc4);
        }
        #pragma unroll
        for (int kk = 0; kk < 32; ++kk) {
            float4 av = *(const float4*)&As[kk * 68 + ty * 4];
            float4 bv = *(const float4*)&Bs[kk * 68 + tx * 4];
            FMA16(av, bv, acc)
        }
        __syncthreads();
    }
}

// softmax-partial epilogue: 4-row groups, re-reads xh patch from global
template<int AMODE>
__device__ __forceinline__ void stats_epi(
    const float* __restrict__ Asrc, const float* __restrict__ maskp,
    const float* abL, const float* caL,
    int r0, int c0, int bx, int t, const float (&acc)[4][4],
    float* __restrict__ pz, float* __restrict__ pa)
{
    const int tx = t & 15, ty = t >> 4;
    const int e = c0 + tx * 4;
    float xh[4][4];
    #pragma unroll
    for (int i = 0; i < 4; ++i) {
        const int r = r0 + ty * 4 + i;
        float4 v = *(const float4*)(Asrc + (size_t)r * 256 + e);
        if (AMODE == 2) {
            const float mv = maskp[r];
            float4 c4 = *(const float4*)(caL + e);
            float4 b4 = *(const float4*)(abL + e);
            v.x = fmaf(mv, v.x + c4.x, b4.x); v.y = fmaf(mv, v.y + c4.y, b4.y);
            v.z = fmaf(mv, v.z + c4.z, b4.z); v.w = fmaf(mv, v.w + c4.w, b4.w);
        }
        xh[i][0] = v.x; xh[i][1] = v.y; xh[i][2] = v.z; xh[i][3] = v.w;
    }
    float pzv[4], pav[4];
    #pragma unroll
    for (int j = 0; j < 4; ++j) {
        float p0 = __expf(acc[0][j]), p1 = __expf(acc[1][j]);
        float p2 = __expf(acc[2][j]), p3 = __expf(acc[3][j]);
        pzv[j] = (p0 + p1) + (p2 + p3);
        pav[j] = fmaf(p0, xh[0][j], fmaf(p1, xh[1][j], fmaf(p2, xh[2][j], p3 * xh[3][j])));
    }
    const int gg = bx * 16 + ty;
    *(float4*)(pz + (size_t)gg * 256 + e) = make_float4(pzv[0], pzv[1], pzv[2], pzv[3]);
    *(float4*)(pa + (size_t)gg * 256 + e) = make_float4(pav[0], pav[1], pav[2], pav[3]);
}

__device__ __forceinline__ void write_epi(float* __restrict__ dst, int r0, int c0,
                                          int t, const float (&acc)[4][4]) {
    const int tx = t & 15, ty = t >> 4;
    const int e = c0 + tx * 4;
    #pragma unroll
    for (int i = 0; i < 4; ++i)
        *(float4*)(dst + (size_t)(r0 + ty * 4 + i) * 256 + e) =
            make_float4(acc[i][0], acc[i][1], acc[i][2], acc[i][3]);
}

// 32x32-tile transpose: dst[k][e] = src[e*sld + scol0 + k]
__device__ inline void transp(const float* __restrict__ src, int sld, int scol0,
                              float* __restrict__ dst, int dld,
                              int ti, int tt, float* lds) {
    const int tr = (ti >> 3) * 32, tc = (ti & 7) * 32;
    const int rr = tt >> 5, cc = tt & 31;
    #pragma unroll
    for (int p = 0; p < 4; ++p) {
        int row = p * 8 + rr;
        lds[row * 33 + cc] = src[(size_t)(tr + row) * sld + scol0 + tc + cc];
    }
    __syncthreads();
    #pragma unroll
    for (int p = 0; p < 4; ++p) {
        int krow = p * 8 + rr;
        dst[(size_t)(tc + krow) * dld + tr + cc] = lds[cc * 33 + krow];
    }
    __syncthreads();
}

// ---------------------------------------------------------------------------
// L0 (unchanged, proven): weight preps + G0
// ---------------------------------------------------------------------------
__global__ __launch_bounds__(256) void l0_k(
    const float* __restrict__ feat, const float* __restrict__ mask,
    const float* __restrict__ agg_w, const float* __restrict__ agg_b,
    const float* __restrict__ attn_w, const float* __restrict__ upd_w,
    const float* __restrict__ upd_b,
    float* __restrict__ wt12, float* __restrict__ u1t, float* __restrict__ u2t,
    float* __restrict__ m2t, float* __restrict__ v0, float* __restrict__ buf0)
{
    const int bid = blockIdx.x, t = threadIdx.x;
    __shared__ __align__(16) float shb[4352];

    if (bid < 128) {
        const int co = (bid < 64) ? 0 : 256;
        const int e0 = (bid & 63) * 4;
        float (&agL)[4][256] = *(float (*)[4][256])shb;
        {
            int row = t >> 6, d0 = (t & 63) * 4;
            *(float4*)&agL[row][d0] = *(const float4*)(agg_w + (size_t)(e0 + row) * 256 + d0);
        }
        __syncthreads();
        float acc[4] = {0.f, 0.f, 0.f, 0.f};
        #pragma unroll 4
        for (int d = 0; d < 256; ++d) {
            float u = upd_w[(size_t)d * 512 + co + t];
            acc[0] = fmaf(agL[0][d], u, acc[0]);
            acc[1] = fmaf(agL[1][d], u, acc[1]);
            acc[2] = fmaf(agL[2][d], u, acc[2]);
            acc[3] = fmaf(agL[3][d], u, acc[3]);
        }
        if (bid < 64) {
            #pragma unroll
            for (int i = 0; i < 4; ++i)
                wt12[(size_t)t * 512 + 256 + e0 + i] = acc[i];     // M1^T
        } else {
            #pragma unroll
            for (int i = 0; i < 4; ++i)
                m2t[(size_t)t * 256 + e0 + i] = acc[i];            // M2^T
        }
    } else if (bid < 192) {
        transp(attn_w, 512, 0, wt12, 512, bid - 128, t, shb);      // W1^T
    } else if (bid < 256) {
        transp(upd_w, 512, 0, u1t, 256, bid - 192, t, shb);        // U1^T
    } else if (bid < 320) {
        transp(upd_w, 512, 256, u2t, 256, bid - 256, t, shb);      // U2^T
    } else if (bid == 320) {
        float* ub = shb;
        ub[t] = upd_b[t];
        __syncthreads();
        float acc = 0.f;
        const float* wr = agg_w + (size_t)t * 256;
        #pragma unroll 8
        for (int d = 0; d < 256; ++d) acc = fmaf(wr[d], ub[d], acc);
        v0[t] = acc;
    } else {
        // G0: xhid_1 = (feat*mask)@agg_w^T + agg_b
        const int v = bid - 321;
        const int r0 = (v & 31) * 64, e0 = (v >> 5) * 64;
        float* As = shb; float* Bs = shb + 2176;
        const int tx = t & 15, ty = t >> 4;
        const int ar = t >> 3, ak = (t & 7) << 2;
        float acc[4][4] = {};
        for (int k0 = 0; k0 < 256; k0 += 32) {
            #pragma unroll
            for (int h = 0; h < 2; ++h) {
                const int row = ar + 32 * h;
                float4 va = *(const float4*)(feat + (size_t)(r0 + row) * 256 + k0 + ak);
                const float mv = mask[r0 + row];
                As[(ak + 0) * 68 + row] = va.x * mv; As[(ak + 1) * 68 + row] = va.y * mv;
                As[(ak + 2) * 68 + row] = va.z * mv; As[(ak + 3) * 68 + row] = va.w * mv;
                float4 vb = *(const float4*)(agg_w + (size_t)(e0 + row) * 256 + k0 + ak);
                Bs[(ak + 0) * 68 + row] = vb.x; Bs[(ak + 1) * 68 + row] = vb.y;
                Bs[(ak + 2) * 68 + row] = vb.z; Bs[(ak + 3) * 68 + row] = vb.w;
            }
            __syncthreads();
            #pragma unroll
            for (int kk = 0; kk < 32; ++kk) {
                float4 av = *(const float4*)&As[kk * 68 + ty * 4];
                float4 bv = *(const float4*)&Bs[kk * 68 + tx * 4];
                FMA16(av, bv, acc)
            }
            __syncthreads();
        }
        const int e = e0 + tx * 4;
        float4 b4 = *(const float4*)(agg_b + e);
        #pragma unroll
        for (int i = 0; i < 4; ++i)
            *(float4*)(buf0 + (size_t)(r0 + ty * 4 + i) * 256 + e) =
                make_float4(acc[i][0] + b4.x, acc[i][1] + b4.y,
                            acc[i][2] + b4.z, acc[i][3] + b4.w);
    }
}

// ---------------------------------------------------------------------------
// BIG1: bx<32: [s1_1|G2_1] GEMM (stats1 / G2_1->buf1).  bx>=32: KS^T prep.
// ---------------------------------------------------------------------------
__global__ __launch_bounds__(256) void big1_k(
    const float* __restrict__ buf0, const float* __restrict__ wt12,
    float* __restrict__ kst, float* __restrict__ buf1,
    float* __restrict__ pz0, float* __restrict__ pa0)
{
    __shared__ __align__(16) float shb[4352];
    const int t = threadIdx.x;
    const int bx = blockIdx.x, by = blockIdx.y;

    if (bx >= 32) {   // KS^T[k][e] = sum_d W1[e,d]*M1[d,k]
        const int k0 = ((bx - 32) * 8 + by) * 4;
        float (&agL)[4][256] = *(float (*)[4][256])shb;
        {
            int row = t >> 6, d0 = (t & 63) * 4;
            *(float4*)&agL[row][d0] =
                *(const float4*)(wt12 + (size_t)(k0 + row) * 512 + 256 + d0);
        }
        __syncthreads();
        float acc[4] = {0.f, 0.f, 0.f, 0.f};
        #pragma unroll 4
        for (int d = 0; d < 256; ++d) {
            float w = wt12[(size_t)d * 512 + t];
            acc[0] = fmaf(agL[0][d], w, acc[0]);
            acc[1] = fmaf(agL[1][d], w, acc[1]);
            acc[2] = fmaf(agL[2][d], w, acc[2]);
            acc[3] = fmaf(agL[3][d], w, acc[3]);
        }
        #pragma unroll
        for (int i = 0; i < 4; ++i)
            kst[(size_t)(k0 + i) * 256 + t] = acc[i];
        return;
    }

    float* As = shb; float* Bs = shb + 2176;
    const int r0 = bx * 64;
    const int c0 = (by < 4) ? by * 64 : 256 + (by - 4) * 64;
    float acc[4][4] = {};
    gemm64<0>(buf0, wt12, 512, c0, r0, nullptr, nullptr, nullptr, As, Bs, t, acc);
    if (by < 4)
        stats_epi<0>(buf0, nullptr, nullptr, nullptr, r0, c0, bx, t, acc, pz0, pa0);
    else
        write_epi(buf1, r0, c0 - 256, t, acc);
}

// ---------------------------------------------------------------------------
// CK1: grid 16, 1024 thr.  agg_1 -> cA_1 -> caG.
// ---------------------------------------------------------------------------
__global__ __launch_bounds__(1024) void ck1_k(
    const float* __restrict__ pz0, const float* __restrict__ pa0,
    const float* __restrict__ m2t, const float* __restrict__ v0,
    float* __restrict__ caG)
{
    __shared__ float zr[4][256], arr[4][256], aggL[256];
    const int tid = threadIdx.x, t = tid & 255, s = tid >> 8;
    const int b = blockIdx.x;
    float z = 0.f, a = 0.f;
    #pragma unroll
    for (int g = 8 * s; g < 8 * s + 8; ++g) {
        size_t idx = (size_t)(b * 32 + g) * 256 + t;
        z += pz0[idx]; a += pa0[idx];
    }
    zr[s][t] = z; arr[s][t] = a;
    __syncthreads();
    if (s == 0) {
        z = (zr[0][t] + zr[1][t]) + (zr[2][t] + zr[3][t]);
        a = (arr[0][t] + arr[1][t]) + (arr[2][t] + arr[3][t]);
        aggL[t] = 1.f / (1.f + __expf(-(a / z)));
    }
    __syncthreads();
    float ca = 0.f;
    #pragma unroll 8
    for (int d = 64 * s; d < 64 * s + 64; ++d)
        ca = fmaf(aggL[d], m2t[(size_t)d * 256 + t], ca);
    zr[s][t] = ca;
    __syncthreads();
    if (s == 0)
        caG[b * 256 + t] = v0[t] + (zr[0][t] + zr[1][t]) + (zr[2][t] + zr[3][t]);
}

// ---------------------------------------------------------------------------
// BIG2: grid (32,12).  caL from caG.  by<4: stats2; 4..7: G2_2->buf0; 8..11: S3->buf2
// ---------------------------------------------------------------------------
__global__ __launch_bounds__(256) void big2_k(
    const float* __restrict__ buf1, const float* __restrict__ wt12,
    const float* __restrict__ kst, const float* __restrict__ caG,
    const float* __restrict__ mask, const float* __restrict__ agg_b,
    float* __restrict__ buf0, float* __restrict__ buf2,
    float* __restrict__ pz1, float* __restrict__ pa1)
{
    __shared__ __align__(16) float shb[4864];
    float* As = shb; float* Bs = shb + 2176;
    float* caL = shb + 4352; float* abL = shb + 4608;

    const int t = threadIdx.x;
    const int bx = blockIdx.x, by = blockIdx.y;
    const int r0 = bx * 64, b = bx >> 1;

    caL[t] = caG[b * 256 + t];
    abL[t] = agg_b[t];
    __syncthreads();

    float acc[4][4] = {};
    if (by < 4) {
        const int c0 = by * 64;
        gemm64<2>(buf1, wt12, 512, c0, r0, mask, abL, caL, As, Bs, t, acc);
        stats_epi<2>(buf1, mask, abL, caL, r0, c0, bx, t, acc, pz1, pa1);
    } else if (by < 8) {
        const int c0 = 256 + (by - 4) * 64;
        gemm64<2>(buf1, wt12, 512, c0, r0, mask, abL, caL, As, Bs, t, acc);
        write_epi(buf0, r0, c0 - 256, t, acc);
    } else {
        const int c0 = (by - 8) * 64;
        gemm64<2>(buf1, kst, 256, c0, r0, mask, abL, caL, As, Bs, t, acc);
        write_epi(buf2, r0, c0, t, acc);
    }
}

// ---------------------------------------------------------------------------
// CK2: grid 16, 1024 thr.  agg_2 -> cA_2 -> caG2;  scan S3/G2_2 -> agg_3 -> c3 -> c3G.
// ---------------------------------------------------------------------------
__global__ __launch_bounds__(1024) void ck2_k(
    const float* __restrict__ pz1, const float* __restrict__ pa1,
    const float* __restrict__ g2, const float* __restrict__ s3,
    const float* __restrict__ m2t, const float* __restrict__ u2t,
    const float* __restrict__ v0, const float* __restrict__ agg_b,
    const float* __restrict__ upd_b,
    float* __restrict__ caG2, float* __restrict__ c3G)
{
    __shared__ float zr[4][256], arr[4][256], aggL[256], caL[256], a3L[256];
    const int tid = threadIdx.x, t = tid & 255, s = tid >> 8;
    const int b = blockIdx.x;

    // agg_2
    float z = 0.f, a = 0.f;
    #pragma unroll
    for (int g = 8 * s; g < 8 * s + 8; ++g) {
        size_t idx = (size_t)(b * 32 + g) * 256 + t;
        z += pz1[idx]; a += pa1[idx];
    }
    zr[s][t] = z; arr[s][t] = a;
    __syncthreads();
    if (s == 0) {
        z = (zr[0][t] + zr[1][t]) + (zr[2][t] + zr[3][t]);
        a = (arr[0][t] + arr[1][t]) + (arr[2][t] + arr[3][t]);
        aggL[t] = 1.f / (1.f + __expf(-(a / z)));
    }
    __syncthreads();
    // cA_2
    float ca = 0.f;
    #pragma unroll 8
    for (int d = 64 * s; d < 64 * s + 64; ++d)
        ca = fmaf(aggL[d], m2t[(size_t)d * 256 + t], ca);
    zr[s][t] = ca;
    __syncthreads();
    if (s == 0) {
        float c = v0[t] + (zr[0][t] + zr[1][t]) + (zr[2][t] + zr[3][t]);
        caL[t] = c;
        caG2[b * 256 + t] = c;
    }
    __syncthreads();
    // scan S3 / G2_2
    float z2 = 0.f, a2 = 0.f;
    const size_t rb = (size_t)b * 128;
    #pragma unroll 4
    for (int r = 32 * s; r < 32 * s + 32; ++r) {
        float p = __expf(s3[(rb + r) * 256 + t]);
        z2 += p;
        a2 = fmaf(p, g2[(rb + r) * 256 + t], a2);
    }
    zr[s][t] = z2; arr[s][t] = a2;
    __syncthreads();
    if (s == 0) {
        z2 = (zr[0][t] + zr[1][t]) + (zr[2][t] + zr[3][t]);
        a2 = (arr[0][t] + arr[1][t]) + (arr[2][t] + arr[3][t]);
        float A3 = a2 / z2 + caL[t] + agg_b[t];
        a3L[t] = 1.f / (1.f + __expf(-A3));
    }
    __syncthreads();
    // c3
    float c3 = 0.f;
    #pragma unroll 8
    for (int d = 64 * s; d < 64 * s + 64; ++d)
        c3 = fmaf(a3L[d], u2t[(size_t)d * 256 + t], c3);
    zr[s][t] = c3;
    __syncthreads();
    if (s == 0)
        c3G[b * 256 + t] = upd_b[t] + (zr[0][t] + zr[1][t]) + (zr[2][t] + zr[3][t]);
}

// ---------------------------------------------------------------------------
// BIG3: grid (64,4), 32x64 tiles, pure GEMM: out = xhid_3 @ U1^T + c3.
// ---------------------------------------------------------------------------
__global__ __launch_bounds__(256) void big3_k(
    const float* __restrict__ buf0, const float* __restrict__ u1t,
    const float* __restrict__ caG2, const float* __restrict__ c3G,
    const float* __restrict__ mask, const float* __restrict__ agg_b,
    float* __restrict__ outp)
{
    __shared__ __align__(16) float shb[3840];
    float* As2 = shb;              // [32][36]
    float* Bs  = shb + 1152;       // [32][68]
    float* caL = shb + 3328;
    float* abL = shb + 3584;

    const int t = threadIdx.x;
    const int bx = blockIdx.x, by = blockIdx.y;
    const int r0 = bx * 32, b = bx >> 2;
    const int c0 = by * 64;

    caL[t] = caG2[b * 256 + t];
    abL[t] = agg_b[t];
    __syncthreads();

    const int tx = t & 15, ty = t >> 4;
    const int ar = t >> 3, ak = (t & 7) << 2;
    const int bk = t >> 4, bc4 = (t & 15) << 2;
    float acc[2][4] = {};
    float4 va, vb0, vb1;
    va  = *(const float4*)(buf0 + (size_t)(r0 + ar) * 256 + ak);
    vb0 = *(const float4*)(u1t + (size_t)bk * 256 + c0 + bc4);
    vb1 = *(const float4*)(u1t + (size_t)(bk + 16) * 256 + c0 + bc4);

    for (int ch = 0; ch < 8; ++ch) {
        const int k0 = ch * 32;
        {
            float4 v = va;
            const float mv = mask[r0 + ar];
            float4 c4 = *(const float4*)(caL + k0 + ak);
            float4 b4 = *(const float4*)(abL + k0 + ak);
            v.x = fmaf(mv, v.x + c4.x, b4.x); v.y = fmaf(mv, v.y + c4.y, b4.y);
            v.z = fmaf(mv, v.z + c4.z, b4.z); v.w = fmaf(mv, v.w + c4.w, b4.w);
            As2[(ak + 0) * 36 + ar] = v.x; As2[(ak + 1) * 36 + ar] = v.y;
            As2[(ak + 2) * 36 + ar] = v.z; As2[(ak + 3) * 36 + ar] = v.w;
            *(float4*)&Bs[bk * 68 + bc4] = vb0;
            *(float4*)&Bs[(bk + 16) * 68 + bc4] = vb1;
        }
        __syncthreads();
        if (ch < 7) {
            const int kn = k0 + 32;
            va  = *(const float4*)(buf0 + (size_t)(r0 + ar) * 256 + kn + ak);
            vb0 = *(const float4*)(u1t + (size_t)(kn + bk) * 256 + c0 + bc4);
            vb1 = *(const float4*)(u1t + (size_t)(kn + bk + 16) * 256 + c0 + bc4);
        }
        #pragma unroll
        for (int kk = 0; kk < 32; ++kk) {
            float2 a2v = *(const float2*)&As2[kk * 36 + ty * 2];
            float4 bv  = *(const float4*)&Bs[kk * 68 + tx * 4];
            acc[0][0]=fmaf(a2v.x,bv.x,acc[0][0]); acc[0][1]=fmaf(a2v.x,bv.y,acc[0][1]);
            acc[0][2]=fmaf(a2v.x,bv.z,acc[0][2]); acc[0][3]=fmaf(a2v.x,bv.w,acc[0][3]);
            acc[1][0]=fmaf(a2v.y,bv.x,acc[1][0]); acc[1][1]=fmaf(a2v.y,bv.y,acc[1][1]);
            acc[1][2]=fmaf(a2v.y,bv.z,acc[1][2]); acc[1][3]=fmaf(a2v.y,bv.w,acc[1][3]);
        }
        __syncthreads();
    }
    const int e = c0 + tx * 4;
    float4 cc = *(const float4*)(c3G + b * 256 + e);
    #pragma unroll
    for (int i = 0; i < 2; ++i)
        *(float4*)(outp + (size_t)(r0 + ty * 2 + i) * 256 + e) =
            make_float4(acc[i][0] + cc.x, acc[i][1] + cc.y,
                        acc[i][2] + cc.z, acc[i][3] + cc.w);
}

// ---------------------------------------------------------------------------
extern "C" void kernel_launch(void* const* d_in, const int* in_sizes, int n_in,
                              void* d_out, int out_size, void* d_ws, size_t ws_size,
                              hipStream_t stream) {
    const float* feat   = (const float*)d_in[0];
    const float* mask   = (const float*)d_in[1];
    const float* agg_w  = (const float*)d_in[2];
    const float* agg_b  = (const float*)d_in[3];
    const float* attn_w = (const float*)d_in[4];   // attn_b (d_in[5]) & W2 cancel
    const float* upd_w  = (const float*)d_in[6];
    const float* upd_b  = (const float*)d_in[7];
    float* out = (float*)d_out;

    float* p    = (float*)d_ws;
    float* wt12 = p; p += 256 * 512;   // [k][ W1^T | M1^T ]
    float* u1t  = p; p += 256 * 256;
    float* u2t  = p; p += 256 * 256;
    float* m2t  = p; p += 256 * 256;
    float* kst  = p; p += 256 * 256;   // KS^T
    float* v0   = p; p += 256;
    float* buf0 = p; p += 2048 * 256;
    float* buf1 = p; p += 2048 * 256;
    float* buf2 = p; p += 2048 * 256;  // S3
    float* pz0  = p; p += 512 * 256;
    float* pa0  = p; p += 512 * 256;
    float* pz1  = p; p += 512 * 256;
    float* pa1  = p; p += 512 * 256;
    float* caG  = p; p += 16 * 256;
    float* caG2 = p; p += 16 * 256;
    float* c3G  = p; p += 16 * 256;

    l0_k<<<449, 256, 0, stream>>>(feat, mask, agg_w, agg_b, attn_w, upd_w, upd_b,
                                  wt12, u1t, u2t, m2t, v0, buf0);
    big1_k<<<dim3(40, 8), 256, 0, stream>>>(buf0, wt12, kst, buf1, pz0, pa0);
    ck1_k<<<16, 1024, 0, stream>>>(pz0, pa0, m2t, v0, caG);
    big2_k<<<dim3(32, 12), 256, 0, stream>>>(buf1, wt12, kst, caG, mask, agg_b,
                                             buf0, buf2, pz1, pa1);
    ck2_k<<<16, 1024, 0, stream>>>(pz1, pa1, buf0, buf2, m2t, u2t, v0, agg_b, upd_b,
                                   caG2, c3G);
    big3_k<<<dim3(64, 4), 256, 0, stream>>>(buf0, u1t, caG2, c3G, mask, agg_b, out);
}